// Round 7
// baseline (659.170 us; speedup 1.0000x reference)
//
#include <hip/hip_runtime.h>
#include <hip/hip_bf16.h>
#include <stdint.h>
#include <stddef.h>

typedef short short8 __attribute__((ext_vector_type(8)));
typedef float f32x4 __attribute__((ext_vector_type(4)));

#define SROWS 65536
#define TROWS 8192
#define HDIM  1024
#define KDIM  2048   // concatenated K: [edu | h]
#define NDIM  4096   // c = 4*j + gate
#define NT    (KDIM / 64)

__device__ __forceinline__ unsigned short f2bf(float f) {
  union { float f; uint32_t u; } v; v.f = f;
  uint32_t u = v.u;
  uint32_t r = (u + 0x7FFFu + ((u >> 16) & 1u)) >> 16;
  return (unsigned short)r;
}

__device__ __forceinline__ float fast_sigmoid(float x) {
  return __builtin_amdgcn_rcpf(1.0f + __builtin_amdgcn_exp2f(-1.44269504f * x));
}
__device__ __forceinline__ float fast_tanh(float x) {
  return 1.0f - 2.0f * __builtin_amdgcn_rcpf(1.0f + __builtin_amdgcn_exp2f(2.88539008f * x));
}

// ---------------- small prep kernels ----------------

__global__ __launch_bounds__(256) void k_initlp(int* lp) {
  int i = blockIdx.x * 256 + threadIdx.x;
  if (i < SROWS) lp[i] = -1;
}

__global__ __launch_bounds__(256) void k_lp(const int* __restrict__ sid, int* lp) {
  int i = blockIdx.x * 256 + threadIdx.x;
  if (i < TROWS) atomicMax(&lp[sid[i]], i);
}

// per-row "untouched" bitmask: bit r of flagb[r>>6] = (lp[r] < 0)
__global__ __launch_bounds__(256) void k_flags(const int* __restrict__ lp,
                                               unsigned long long* __restrict__ flagb) {
  int i = blockIdx.x * 256 + threadIdx.x;
  unsigned long long m = __ballot(lp[i] < 0);
  if ((threadIdx.x & 63) == 0) flagb[i >> 6] = m;
}

__global__ __launch_bounds__(256) void k_bias(const float* __restrict__ bih,
                                              const float* __restrict__ bhh,
                                              float* __restrict__ btab) {
  int j = blockIdx.x * 256 + threadIdx.x;
  if (j < HDIM) {
    btab[4*j+0] = bih[j] + bhh[j];
    btab[4*j+1] = bih[j+HDIM] + bhh[j+HDIM];
    btab[4*j+2] = bih[j+2*HDIM];
    btab[4*j+3] = bhh[j+2*HDIM];
  }
}

__global__ __launch_bounds__(256) void k_build_A(const float* __restrict__ edu,
                                                 const float* __restrict__ mem,
                                                 const int* __restrict__ sid,
                                                 unsigned short* __restrict__ Ac) {
  const int idx = blockIdx.x * 256 + threadIdx.x;
  const int t  = idx >> 8;
  const int k0 = (idx & 255) << 3;
  const float* src;
  if (k0 < HDIM) src = edu + (size_t)t * HDIM + k0;
  else           src = mem + (size_t)sid[t] * HDIM + (k0 - HDIM);
  f32x4 f0 = *(const f32x4*)src;
  f32x4 f1 = *(const f32x4*)(src + 4);
  short8 v;
  v[0]=(short)f2bf(f0[0]); v[1]=(short)f2bf(f0[1]); v[2]=(short)f2bf(f0[2]); v[3]=(short)f2bf(f0[3]);
  v[4]=(short)f2bf(f1[0]); v[5]=(short)f2bf(f1[1]); v[6]=(short)f2bf(f1[2]); v[7]=(short)f2bf(f1[3]);
  *(short8*)(Ac + (size_t)idx * 8) = v;
}

__global__ __launch_bounds__(256) void k_build_B(const float* __restrict__ Wih,
                                                 const float* __restrict__ Whh,
                                                 unsigned short* __restrict__ Bc) {
  const int idx = blockIdx.x * 256 + threadIdx.x;
  const int c  = idx >> 8;
  const int k0 = (idx & 255) << 3;
  const int j  = c >> 2;
  const int g  = c & 3;
  const float* src = nullptr;
  if (g == 0)      src = (k0 < HDIM) ? Wih + (size_t)j * HDIM + k0
                                     : Whh + (size_t)j * HDIM + (k0 - HDIM);
  else if (g == 1) src = (k0 < HDIM) ? Wih + (size_t)(j + HDIM) * HDIM + k0
                                     : Whh + (size_t)(j + HDIM) * HDIM + (k0 - HDIM);
  else if (g == 2) { if (k0 < HDIM)  src = Wih + (size_t)(j + 2*HDIM) * HDIM + k0; }
  else             { if (k0 >= HDIM) src = Whh + (size_t)(j + 2*HDIM) * HDIM + (k0 - HDIM); }
  short8 v = (short8)0;
  if (src) {
    f32x4 f0 = *(const f32x4*)src;
    f32x4 f1 = *(const f32x4*)(src + 4);
    v[0]=(short)f2bf(f0[0]); v[1]=(short)f2bf(f0[1]); v[2]=(short)f2bf(f0[2]); v[3]=(short)f2bf(f0[3]);
    v[4]=(short)f2bf(f1[0]); v[5]=(short)f2bf(f1[1]); v[6]=(short)f2bf(f1[2]); v[7]=(short)f2bf(f1[3]);
  }
  *(short8*)(Bc + (size_t)idx * 8) = v;
}

// ---------------- wave-specialized GEMM + copy ----------------
// 768 threads: waves 0..7 = 256x256 8-phase GEMM (BK=64, counted vmcnt(4),
// (row&7)<<4 swizzle both sides, setprio); waves 8..11 = barrier-matched
// nt streaming copy of this block's 128 untouched rows.
// Barrier ledger: GEMM = 1 + 32*8 + 1 + 16 = 274 ; copy = 127*2 + 2 + 18 = 274.

#define FENCE() asm volatile("" ::: "memory")
#define BAR()   __builtin_amdgcn_s_barrier()
#define LGKM0() asm volatile("s_waitcnt lgkmcnt(0)" ::: "memory")
#define VM(N)   asm volatile("s_waitcnt vmcnt(" #N ")" ::: "memory")

#define STAGE(p0, p1, ldsoff)                                                              \
  __builtin_amdgcn_global_load_lds((const __attribute__((address_space(1))) void*)(p0),   \
      (__attribute__((address_space(3))) void*)(smem + (ldsoff) + w * 1024), 16, 0, 0);    \
  __builtin_amdgcn_global_load_lds((const __attribute__((address_space(1))) void*)(p1),   \
      (__attribute__((address_space(3))) void*)(smem + (ldsoff) + 8192 + w * 1024), 16, 0, 0);

#define LDF(base, frag, koff) (*(const short8*)(smem + (base) + (size_t)(frag) * 2048 + (koff)))

__global__ __launch_bounds__(768, 3)
void k_fused(const unsigned short* __restrict__ Ac,
             const unsigned short* __restrict__ Bc,
             const float* __restrict__ mem,
             const int* __restrict__ sid,
             const int* __restrict__ lp,
             const unsigned long long* __restrict__ flagb,
             const float* __restrict__ btab,
             float* __restrict__ out) {
  extern __shared__ char smem[];
  const int tid = threadIdx.x;
  const int bid = blockIdx.x;
  const int w   = tid >> 6;

  if (w >= 8) {
    // ================= copy waves (8..11): 128 rows/block, barrier-matched =================
    const int ct    = tid - 512;            // 0..255
    const int col   = ct << 2;              // f32 column
    const int rbase = bid << 7;             // 128 rows per block
    const unsigned long long f0 = flagb[bid * 2];
    const unsigned long long f1 = flagb[bid * 2 + 1];

    bool pv = (f0 & 1ull) != 0;
    f32x4 d = {0.f, 0.f, 0.f, 0.f};
    if (pv) d = __builtin_nontemporal_load((const f32x4*)&mem[(size_t)rbase * HDIM + col]);
    for (int r = 1; r < 128; ++r) {
      const unsigned long long fw = (r < 64) ? f0 : f1;
      const bool v = (fw >> (r & 63)) & 1ull;
      f32x4 nd = {0.f, 0.f, 0.f, 0.f};
      if (v)  nd = __builtin_nontemporal_load((const f32x4*)&mem[(size_t)(rbase + r) * HDIM + col]);
      if (pv) __builtin_nontemporal_store(d, (f32x4*)&out[(size_t)(rbase + r - 1) * HDIM + col]);
      pv = v; d = nd;
      BAR(); BAR();                         // 127*2 = 254
    }
    if (pv) __builtin_nontemporal_store(d, (f32x4*)&out[(size_t)(rbase + 127) * HDIM + col]);
    BAR(); BAR();                           // 256
    for (int i = 0; i < 18; ++i) BAR();     // 274
    return;
  }

  // ================= GEMM waves (0..7) =================
  const int lane = tid & 63;
  const int wm   = w >> 2;        // M half (0..1)
  const int wn   = w & 3;         // N quarter (0..3)
  const int l15  = lane & 15;
  const int l4   = lane >> 4;

  // XCD-aware swizzle (512 % 8 == 0 -> bijective)
  const int swz = (bid & 7) * 64 + (bid >> 3);
  const int t0  = (swz >> 4) * 256;
  const int c0  = (swz & 15) * 256;

  // ---- staging source mapping (inverse (row&7)<<4 swizzle folded in) ----
  const int srow0 = tid >> 3;
  const int srow1 = 64 + srow0;
  const int scol  = ((tid & 7) * 8) ^ (((tid >> 3) & 7) << 3);

  const unsigned short* pA0r0 = Ac + (size_t)(t0 +       srow0) * KDIM + scol;
  const unsigned short* pA0r1 = Ac + (size_t)(t0 +       srow1) * KDIM + scol;
  const unsigned short* pA1r0 = Ac + (size_t)(t0 + 128 + srow0) * KDIM + scol;
  const unsigned short* pA1r1 = Ac + (size_t)(t0 + 128 + srow1) * KDIM + scol;
  const unsigned short* pB0r0 = Bc + (size_t)(c0 +       srow0) * KDIM + scol;
  const unsigned short* pB0r1 = Bc + (size_t)(c0 +       srow1) * KDIM + scol;
  const unsigned short* pB1r0 = Bc + (size_t)(c0 + 128 + srow0) * KDIM + scol;
  const unsigned short* pB1r1 = Bc + (size_t)(c0 + 128 + srow1) * KDIM + scol;

  // ---- fragment read offsets: col_byte ^= (row&7)<<4 ----
  const int rsw = (l15 & 7) << 4;
  const size_t foff0 = (size_t)l15 * 128 + ((l4 * 16)      ^ rsw);
  const size_t foff1 = (size_t)l15 * 128 + ((64 + l4 * 16) ^ rsw);

  f32x4 acc[8][4];
#pragma unroll
  for (int i = 0; i < 8; i++)
#pragma unroll
    for (int j = 0; j < 4; j++) acc[i][j] = (f32x4){0.f, 0.f, 0.f, 0.f};

  // ---- prologue: tile0 (A0,A1,B0,B1) + tile1 (B0,B1)
  STAGE(pA0r0, pA0r1, 0);
  STAGE(pA1r0, pA1r1, 16384);
  STAGE(pB0r0, pB0r1, 32768);
  STAGE(pB1r0, pB1r1, 49152);
  STAGE(pB0r0 + 64, pB0r1 + 64, 65536 + 32768);
  STAGE(pB1r0 + 64, pB1r1 + 64, 65536 + 49152);
  VM(4);
  FENCE(); BAR();                                   // 1

  for (int t = 0; t < NT; ++t) {
    const int cur = t & 1, nxt = cur ^ 1;
    const size_t abase = (size_t)cur * 65536 + (size_t)wm * 16384;
    const size_t bbase = (size_t)cur * 65536 + 32768 + (size_t)(wn >> 1) * 16384
                       + (size_t)(wn & 1) * 8192;
    const int kt1 = (t + 1 < NT) ? t + 1 : NT - 1;
    const int kt2 = (t + 2 < NT) ? t + 2 : NT - 1;

    short8 bf[4][2];
#pragma unroll
    for (int q = 0; q < 4; q++) {
      const int m0 = 2 * q;
      if (q == 0) {
#pragma unroll
        for (int n = 0; n < 4; n++) {
          bf[n][0] = LDF(bbase, n, foff0);
          bf[n][1] = LDF(bbase, n, foff1);
        }
      }
      short8 af[2][2];
      af[0][0] = LDF(abase, m0,     foff0);
      af[0][1] = LDF(abase, m0,     foff1);
      af[1][0] = LDF(abase, m0 + 1, foff0);
      af[1][1] = LDF(abase, m0 + 1, foff1);

      if (q == 0)      { STAGE(pA0r0 + kt1 * 64, pA0r1 + kt1 * 64, (size_t)nxt * 65536); }
      else if (q == 1) { STAGE(pA1r0 + kt1 * 64, pA1r1 + kt1 * 64, (size_t)nxt * 65536 + 16384); }
      else if (q == 2) { STAGE(pB0r0 + kt2 * 64, pB0r1 + kt2 * 64, (size_t)cur * 65536 + 32768); }
      else             { STAGE(pB1r0 + kt2 * 64, pB1r1 + kt2 * 64, (size_t)cur * 65536 + 49152); }

      FENCE(); BAR();                               // 8 per tile (2 per phase)
      LGKM0();
      __builtin_amdgcn_s_setprio(1);
#pragma unroll
      for (int i = 0; i < 2; i++)
#pragma unroll
        for (int n = 0; n < 4; n++) {
          acc[m0 + i][n] = __builtin_amdgcn_mfma_f32_16x16x32_bf16(af[i][0], bf[n][0], acc[m0 + i][n], 0, 0, 0);
          acc[m0 + i][n] = __builtin_amdgcn_mfma_f32_16x16x32_bf16(af[i][1], bf[n][1], acc[m0 + i][n], 0, 0, 0);
        }
      __builtin_amdgcn_s_setprio(0);
      if (q == 3) { VM(4); }
      FENCE(); BAR();
    }
  }

  // ---- drain + epilogue: LDS transpose per 16-row chunk, gates, guarded scatter
  VM(0);
  __syncthreads();                                  // 1
  float* epi = (float*)smem;   // [8 waves][16][68]
  const int jfirst = ((c0 + wn * 64) >> 2) + l4 * 4;

#pragma unroll
  for (int mf = 0; mf < 8; mf++) {
#pragma unroll
    for (int nf = 0; nf < 4; nf++)
#pragma unroll
      for (int r = 0; r < 4; r++)
        epi[w * 1088 + (l4 * 4 + r) * 68 + nf * 16 + l15] = acc[mf][nf][r];
    __syncthreads();                                // 8x

    const int trow = t0 + wm * 128 + mf * 16 + l15;
    const int s    = sid[trow];
    const bool wr  = (lp[s] == trow);

    f32x4 q[4];
#pragma unroll
    for (int jj = 0; jj < 4; jj++)
      q[jj] = *(const f32x4*)&epi[w * 1088 + l15 * 68 + l4 * 16 + jj * 4];

    f32x4 hv = *(const f32x4*)&mem[(size_t)s * HDIM + jfirst];
    f32x4 o;
#pragma unroll
    for (int jj = 0; jj < 4; jj++) {
      const int j = jfirst + jj;
      f32x4 bt = *(const f32x4*)&btab[4 * j];
      float rr = fast_sigmoid(q[jj][0] + bt[0]);
      float zz = fast_sigmoid(q[jj][1] + bt[1]);
      float nn = fast_tanh(q[jj][2] + bt[2] + rr * (q[jj][3] + bt[3]));
      o[jj] = (1.0f - zz) * nn + zz * hv[jj];
    }
    if (wr) __builtin_nontemporal_store(o, (f32x4*)&out[(size_t)s * HDIM + jfirst]);
    __syncthreads();                                // 8x
  }
}

// ---------------- launch ----------------

extern "C" void kernel_launch(void* const* d_in, const int* in_sizes, int n_in,
                              void* d_out, int out_size, void* d_ws, size_t ws_size,
                              hipStream_t stream) {
  const float* mem = (const float*)d_in[0];
  const int*   sid = (const int*)d_in[1];
  const float* edu = (const float*)d_in[2];
  const float* Wih = (const float*)d_in[3];
  const float* Whh = (const float*)d_in[4];
  const float* bih = (const float*)d_in[5];
  const float* bhh = (const float*)d_in[6];
  float* out = (float*)d_out;

  char* p = (char*)d_ws;
  unsigned short* Ac = (unsigned short*)p; p += (size_t)TROWS * KDIM * 2;   // 32 MiB
  unsigned short* Bc = (unsigned short*)p; p += (size_t)NDIM * KDIM * 2;    // 16 MiB
  int*   lp   = (int*)p;   p += (size_t)SROWS * 4;                          // 256 KiB
  float* btab = (float*)p; p += (size_t)HDIM * 4 * 4;                       // 16 KiB
  unsigned long long* flagb = (unsigned long long*)p; p += (size_t)(SROWS / 64) * 8; // 8 KiB

  hipFuncSetAttribute((const void*)k_fused, hipFuncAttributeMaxDynamicSharedMemorySize, 131072);

  hipLaunchKernelGGL(k_initlp, dim3(SROWS / 256), dim3(256), 0, stream, lp);
  hipLaunchKernelGGL(k_lp, dim3(TROWS / 256), dim3(256), 0, stream, sid, lp);
  hipLaunchKernelGGL(k_flags, dim3(SROWS / 256), dim3(256), 0, stream, lp, flagb);
  hipLaunchKernelGGL(k_bias, dim3(4), dim3(256), 0, stream, bih, bhh, btab);
  hipLaunchKernelGGL(k_build_A, dim3((TROWS * KDIM / 8) / 256), dim3(256), 0, stream, edu, mem, sid, Ac);
  hipLaunchKernelGGL(k_build_B, dim3((NDIM * KDIM / 8) / 256), dim3(256), 0, stream, Wih, Whh, Bc);
  hipLaunchKernelGGL(k_fused, dim3(512), dim3(768), 131072, stream,
                     Ac, Bc, mem, sid, lp, flagb, btab, out);
}

// Round 8
// 243.253 us; speedup vs baseline: 2.7098x; 2.7098x over previous
//
#include <hip/hip_runtime.h>
#include <hip/hip_bf16.h>
#include <stdint.h>
#include <stddef.h>

typedef short short8 __attribute__((ext_vector_type(8)));
typedef float f32x4 __attribute__((ext_vector_type(4)));

#define SROWS 65536
#define TROWS 8192
#define HDIM  1024
#define KDIM  2048   // concatenated K: [edu | h]
#define NDIM  4096   // c = 4*j + gate
#define NT    (KDIM / 64)

__device__ __forceinline__ unsigned short f2bf(float f) {
  union { float f; uint32_t u; } v; v.f = f;
  uint32_t u = v.u;
  uint32_t r = (u + 0x7FFFu + ((u >> 16) & 1u)) >> 16;
  return (unsigned short)r;
}

__device__ __forceinline__ float fast_sigmoid(float x) {
  return __builtin_amdgcn_rcpf(1.0f + __builtin_amdgcn_exp2f(-1.44269504f * x));
}
__device__ __forceinline__ float fast_tanh(float x) {
  return 1.0f - 2.0f * __builtin_amdgcn_rcpf(1.0f + __builtin_amdgcn_exp2f(2.88539008f * x));
}

// ---------------- small prep kernels ----------------

__global__ __launch_bounds__(256) void k_initlp(int* lp) {
  int i = blockIdx.x * 256 + threadIdx.x;
  if (i < SROWS) lp[i] = -1;
}

__global__ __launch_bounds__(256) void k_lp(const int* __restrict__ sid, int* lp) {
  int i = blockIdx.x * 256 + threadIdx.x;
  if (i < TROWS) atomicMax(&lp[sid[i]], i);
}

__global__ __launch_bounds__(256) void k_bias(const float* __restrict__ bih,
                                              const float* __restrict__ bhh,
                                              float* __restrict__ btab) {
  int j = blockIdx.x * 256 + threadIdx.x;
  if (j < HDIM) {
    btab[4*j+0] = bih[j] + bhh[j];
    btab[4*j+1] = bih[j+HDIM] + bhh[j+HDIM];
    btab[4*j+2] = bih[j+2*HDIM];
    btab[4*j+3] = bhh[j+2*HDIM];
  }
}

__global__ __launch_bounds__(256) void k_build_A(const float* __restrict__ edu,
                                                 const float* __restrict__ mem,
                                                 const int* __restrict__ sid,
                                                 unsigned short* __restrict__ Ac) {
  const int idx = blockIdx.x * 256 + threadIdx.x;
  const int t  = idx >> 8;
  const int k0 = (idx & 255) << 3;
  const float* src;
  if (k0 < HDIM) src = edu + (size_t)t * HDIM + k0;
  else           src = mem + (size_t)sid[t] * HDIM + (k0 - HDIM);
  f32x4 f0 = *(const f32x4*)src;
  f32x4 f1 = *(const f32x4*)(src + 4);
  short8 v;
  v[0]=(short)f2bf(f0[0]); v[1]=(short)f2bf(f0[1]); v[2]=(short)f2bf(f0[2]); v[3]=(short)f2bf(f0[3]);
  v[4]=(short)f2bf(f1[0]); v[5]=(short)f2bf(f1[1]); v[6]=(short)f2bf(f1[2]); v[7]=(short)f2bf(f1[3]);
  *(short8*)(Ac + (size_t)idx * 8) = v;
}

__global__ __launch_bounds__(256) void k_build_B(const float* __restrict__ Wih,
                                                 const float* __restrict__ Whh,
                                                 unsigned short* __restrict__ Bc) {
  const int idx = blockIdx.x * 256 + threadIdx.x;
  const int c  = idx >> 8;
  const int k0 = (idx & 255) << 3;
  const int j  = c >> 2;
  const int g  = c & 3;
  const float* src = nullptr;
  if (g == 0)      src = (k0 < HDIM) ? Wih + (size_t)j * HDIM + k0
                                     : Whh + (size_t)j * HDIM + (k0 - HDIM);
  else if (g == 1) src = (k0 < HDIM) ? Wih + (size_t)(j + HDIM) * HDIM + k0
                                     : Whh + (size_t)(j + HDIM) * HDIM + (k0 - HDIM);
  else if (g == 2) { if (k0 < HDIM)  src = Wih + (size_t)(j + 2*HDIM) * HDIM + k0; }
  else             { if (k0 >= HDIM) src = Whh + (size_t)(j + 2*HDIM) * HDIM + (k0 - HDIM); }
  short8 v = (short8)0;
  if (src) {
    f32x4 f0 = *(const f32x4*)src;
    f32x4 f1 = *(const f32x4*)(src + 4);
    v[0]=(short)f2bf(f0[0]); v[1]=(short)f2bf(f0[1]); v[2]=(short)f2bf(f0[2]); v[3]=(short)f2bf(f0[3]);
    v[4]=(short)f2bf(f1[0]); v[5]=(short)f2bf(f1[1]); v[6]=(short)f2bf(f1[2]); v[7]=(short)f2bf(f1[3]);
  }
  *(short8*)(Bc + (size_t)idx * 8) = v;
}

// non-temporal streaming copy of untouched rows (r1 pattern, ~6 TB/s)
__global__ __launch_bounds__(256) void k_copy(const float* __restrict__ mem,
                                              const int* __restrict__ lp,
                                              float* __restrict__ out) {
  for (int s = blockIdx.x; s < SROWS; s += gridDim.x) {
    if (lp[s] >= 0) continue;
    const f32x4* src = (const f32x4*)(mem + (size_t)s * HDIM);
    f32x4* dst = (f32x4*)(out + (size_t)s * HDIM);
    f32x4 v = __builtin_nontemporal_load(src + threadIdx.x);
    __builtin_nontemporal_store(v, dst + threadIdx.x);
  }
}

// ---------------- 256x256 8-phase GEMM + gates + scatter (NO copy) ----------------
// BM=BN=256, BK=64, 8 waves (2M x 4N), 128 KiB dynamic LDS (2 buf x (A 32K | B 32K)),
// (row&7)<<4 XOR swizzle both sides (verified r3: conflicts 1.3e7 -> 5.2e5),
// counted vmcnt(4) once per K-tile, setprio around MFMA.

#define FENCE() asm volatile("" ::: "memory")
#define BAR()   __builtin_amdgcn_s_barrier()
#define LGKM0() asm volatile("s_waitcnt lgkmcnt(0)" ::: "memory")
#define VM(N)   asm volatile("s_waitcnt vmcnt(" #N ")" ::: "memory")

#define STAGE(p0, p1, ldsoff)                                                              \
  __builtin_amdgcn_global_load_lds((const __attribute__((address_space(1))) void*)(p0),   \
      (__attribute__((address_space(3))) void*)(smem + (ldsoff) + w * 1024), 16, 0, 0);    \
  __builtin_amdgcn_global_load_lds((const __attribute__((address_space(1))) void*)(p1),   \
      (__attribute__((address_space(3))) void*)(smem + (ldsoff) + 8192 + w * 1024), 16, 0, 0);

#define LDF(base, frag, koff) (*(const short8*)(smem + (base) + (size_t)(frag) * 2048 + (koff)))

__global__ __launch_bounds__(512, 2)
void k_gru8(const unsigned short* __restrict__ Ac,
            const unsigned short* __restrict__ Bc,
            const float* __restrict__ mem,
            const int* __restrict__ sid,
            const int* __restrict__ lp,
            const float* __restrict__ btab,
            float* __restrict__ out) {
  extern __shared__ char smem[];

  const int tid  = threadIdx.x;
  const int lane = tid & 63;
  const int w    = tid >> 6;
  const int wm   = w >> 2;        // M half (0..1)
  const int wn   = w & 3;         // N quarter (0..3)
  const int l15  = lane & 15;
  const int l4   = lane >> 4;

  // XCD-aware swizzle (512 % 8 == 0 -> bijective)
  const int bid = blockIdx.x;
  const int swz = (bid & 7) * 64 + (bid >> 3);
  const int t0  = (swz >> 4) * 256;
  const int c0  = (swz & 15) * 256;

  // ---- staging source mapping (inverse (row&7)<<4 swizzle folded in) ----
  const int srow0 = tid >> 3;
  const int srow1 = 64 + srow0;
  const int scol  = ((tid & 7) * 8) ^ (((tid >> 3) & 7) << 3);

  const unsigned short* pA0r0 = Ac + (size_t)(t0 +       srow0) * KDIM + scol;
  const unsigned short* pA0r1 = Ac + (size_t)(t0 +       srow1) * KDIM + scol;
  const unsigned short* pA1r0 = Ac + (size_t)(t0 + 128 + srow0) * KDIM + scol;
  const unsigned short* pA1r1 = Ac + (size_t)(t0 + 128 + srow1) * KDIM + scol;
  const unsigned short* pB0r0 = Bc + (size_t)(c0 +       srow0) * KDIM + scol;
  const unsigned short* pB0r1 = Bc + (size_t)(c0 +       srow1) * KDIM + scol;
  const unsigned short* pB1r0 = Bc + (size_t)(c0 + 128 + srow0) * KDIM + scol;
  const unsigned short* pB1r1 = Bc + (size_t)(c0 + 128 + srow1) * KDIM + scol;

  // ---- fragment read offsets: col_byte ^= (row&7)<<4 ----
  const int rsw = (l15 & 7) << 4;
  const size_t foff0 = (size_t)l15 * 128 + ((l4 * 16)      ^ rsw);
  const size_t foff1 = (size_t)l15 * 128 + ((64 + l4 * 16) ^ rsw);

  f32x4 acc[8][4];
#pragma unroll
  for (int i = 0; i < 8; i++)
#pragma unroll
    for (int j = 0; j < 4; j++) acc[i][j] = (f32x4){0.f, 0.f, 0.f, 0.f};

  // ---- prologue: tile0 (A0,A1,B0,B1) + tile1 (B0,B1)
  STAGE(pA0r0, pA0r1, 0);
  STAGE(pA1r0, pA1r1, 16384);
  STAGE(pB0r0, pB0r1, 32768);
  STAGE(pB1r0, pB1r1, 49152);
  STAGE(pB0r0 + 64, pB0r1 + 64, 65536 + 32768);
  STAGE(pB1r0 + 64, pB1r1 + 64, 65536 + 49152);
  VM(4);
  FENCE(); BAR();

  for (int t = 0; t < NT; ++t) {
    const int cur = t & 1, nxt = cur ^ 1;
    const size_t abase = (size_t)cur * 65536 + (size_t)wm * 16384;
    const size_t bbase = (size_t)cur * 65536 + 32768 + (size_t)(wn >> 1) * 16384
                       + (size_t)(wn & 1) * 8192;
    const int kt1 = (t + 1 < NT) ? t + 1 : NT - 1;
    const int kt2 = (t + 2 < NT) ? t + 2 : NT - 1;

    short8 bf[4][2];
#pragma unroll
    for (int q = 0; q < 4; q++) {
      const int m0 = 2 * q;
      if (q == 0) {
#pragma unroll
        for (int n = 0; n < 4; n++) {
          bf[n][0] = LDF(bbase, n, foff0);
          bf[n][1] = LDF(bbase, n, foff1);
        }
      }
      short8 af[2][2];
      af[0][0] = LDF(abase, m0,     foff0);
      af[0][1] = LDF(abase, m0,     foff1);
      af[1][0] = LDF(abase, m0 + 1, foff0);
      af[1][1] = LDF(abase, m0 + 1, foff1);

      if (q == 0)      { STAGE(pA0r0 + kt1 * 64, pA0r1 + kt1 * 64, (size_t)nxt * 65536); }
      else if (q == 1) { STAGE(pA1r0 + kt1 * 64, pA1r1 + kt1 * 64, (size_t)nxt * 65536 + 16384); }
      else if (q == 2) { STAGE(pB0r0 + kt2 * 64, pB0r1 + kt2 * 64, (size_t)cur * 65536 + 32768); }
      else             { STAGE(pB1r0 + kt2 * 64, pB1r1 + kt2 * 64, (size_t)cur * 65536 + 49152); }

      FENCE(); BAR();
      LGKM0();
      __builtin_amdgcn_s_setprio(1);
#pragma unroll
      for (int i = 0; i < 2; i++)
#pragma unroll
        for (int n = 0; n < 4; n++) {
          acc[m0 + i][n] = __builtin_amdgcn_mfma_f32_16x16x32_bf16(af[i][0], bf[n][0], acc[m0 + i][n], 0, 0, 0);
          acc[m0 + i][n] = __builtin_amdgcn_mfma_f32_16x16x32_bf16(af[i][1], bf[n][1], acc[m0 + i][n], 0, 0, 0);
        }
      __builtin_amdgcn_s_setprio(0);
      if (q == 3) { VM(4); }
      FENCE(); BAR();
    }
  }

  // ---- drain + epilogue: LDS transpose per 16-row chunk, gates, guarded scatter
  VM(0);
  __syncthreads();
  float* epi = (float*)smem;   // [8 waves][16][68]
  const int jfirst = ((c0 + wn * 64) >> 2) + l4 * 4;

#pragma unroll
  for (int mf = 0; mf < 8; mf++) {
#pragma unroll
    for (int nf = 0; nf < 4; nf++)
#pragma unroll
      for (int r = 0; r < 4; r++)
        epi[w * 1088 + (l4 * 4 + r) * 68 + nf * 16 + l15] = acc[mf][nf][r];
    __syncthreads();

    const int trow = t0 + wm * 128 + mf * 16 + l15;
    const int s    = sid[trow];
    const bool wr  = (lp[s] == trow);

    f32x4 q[4];
#pragma unroll
    for (int jj = 0; jj < 4; jj++)
      q[jj] = *(const f32x4*)&epi[w * 1088 + l15 * 68 + l4 * 16 + jj * 4];

    f32x4 hv = *(const f32x4*)&mem[(size_t)s * HDIM + jfirst];
    f32x4 o;
#pragma unroll
    for (int jj = 0; jj < 4; jj++) {
      const int j = jfirst + jj;
      f32x4 bt = *(const f32x4*)&btab[4 * j];
      float rr = fast_sigmoid(q[jj][0] + bt[0]);
      float zz = fast_sigmoid(q[jj][1] + bt[1]);
      float nn = fast_tanh(q[jj][2] + bt[2] + rr * (q[jj][3] + bt[3]));
      o[jj] = (1.0f - zz) * nn + zz * hv[jj];
    }
    if (wr) __builtin_nontemporal_store(o, (f32x4*)&out[(size_t)s * HDIM + jfirst]);
    __syncthreads();
  }
}

// ---------------- launch ----------------

extern "C" void kernel_launch(void* const* d_in, const int* in_sizes, int n_in,
                              void* d_out, int out_size, void* d_ws, size_t ws_size,
                              hipStream_t stream) {
  const float* mem = (const float*)d_in[0];
  const int*   sid = (const int*)d_in[1];
  const float* edu = (const float*)d_in[2];
  const float* Wih = (const float*)d_in[3];
  const float* Whh = (const float*)d_in[4];
  const float* bih = (const float*)d_in[5];
  const float* bhh = (const float*)d_in[6];
  float* out = (float*)d_out;

  char* p = (char*)d_ws;
  unsigned short* Ac = (unsigned short*)p; p += (size_t)TROWS * KDIM * 2;   // 32 MiB
  unsigned short* Bc = (unsigned short*)p; p += (size_t)NDIM * KDIM * 2;    // 16 MiB
  int*   lp   = (int*)p;   p += (size_t)SROWS * 4;                          // 256 KiB
  float* btab = (float*)p; p += (size_t)HDIM * 4 * 4;                       // 16 KiB

  hipFuncSetAttribute((const void*)k_gru8, hipFuncAttributeMaxDynamicSharedMemorySize, 131072);

  hipLaunchKernelGGL(k_initlp, dim3(SROWS / 256), dim3(256), 0, stream, lp);
  hipLaunchKernelGGL(k_lp, dim3(TROWS / 256), dim3(256), 0, stream, sid, lp);
  hipLaunchKernelGGL(k_bias, dim3(4), dim3(256), 0, stream, bih, bhh, btab);
  hipLaunchKernelGGL(k_build_A, dim3((TROWS * KDIM / 8) / 256), dim3(256), 0, stream, edu, mem, sid, Ac);
  hipLaunchKernelGGL(k_build_B, dim3((NDIM * KDIM / 8) / 256), dim3(256), 0, stream, Wih, Whh, Bc);
  hipLaunchKernelGGL(k_copy, dim3(8192), dim3(256), 0, stream, mem, lp, out);
  hipLaunchKernelGGL(k_gru8, dim3(512), dim3(512), 131072, stream,
                     Ac, Bc, mem, sid, lp, btab, out);
}